// Round 8
// baseline (486.940 us; speedup 1.0000x reference)
//
#include <hip/hip_runtime.h>
#include <hip/hip_bf16.h>
#include <math.h>

// Problem constants
constexpr int cB   = 4;
constexpr int cL   = 1024;
constexpr int cH   = 1024;
constexpr int cA   = 16;
constexpr int cM   = 128;
constexpr int cE   = 32;
constexpr int cR   = 992;
constexpr int cEMB = 768;
constexpr int cC   = 97;
constexpr int cN   = cB * cR;   // 3968

typedef unsigned short ushort;
typedef __attribute__((ext_vector_type(4))) unsigned short ushort4v;
typedef __attribute__((ext_vector_type(8))) short short8;
typedef __attribute__((ext_vector_type(4))) float float4v;

static __device__ inline float bf2f(ushort u) {
    unsigned v = ((unsigned)u) << 16;
    float f;
    __builtin_memcpy(&f, &v, 4);
    return f;
}
static __device__ inline ushort f2bf(float f) {
    unsigned u;
    __builtin_memcpy(&u, &f, 4);
    unsigned r = (u + 0x7FFFu + ((u >> 16) & 1u)) >> 16;
    return (ushort)r;
}

// ---------------------------------------------------------------------------
// Generic transpose f32 -> bf16: src[z][R][C] -> dst[z][Cp][R], zero-pad c>=C
__global__ void tr_bf16_k(const float* __restrict__ src, ushort* __restrict__ dst,
                          int R, int C, int Cp) {
    int z = blockIdx.z;
    int r0 = blockIdx.x * 32, c0 = blockIdx.y * 32;
    int tx = threadIdx.x & 31, ty = threadIdx.x >> 5;  // ty 0..7
    __shared__ float tile[32][33];
    for (int p = 0; p < 4; p++) {
        int r = r0 + ty + p * 8, c = c0 + tx;
        tile[ty + p * 8][tx] = (r < R && c < C) ? src[((size_t)z * R + r) * C + c] : 0.f;
    }
    __syncthreads();
    for (int p = 0; p < 4; p++) {
        int c = c0 + ty + p * 8, r = r0 + tx;
        if (c < Cp && r < R)
            dst[((size_t)z * Cp + c) * R + r] = f2bf(tile[tx][ty + p * 8]);
    }
}

// Head+tail weight transpose in one launch (z selects which matrix)
__global__ void tr_ht_k(const float* __restrict__ Wh, const float* __restrict__ Wt,
                        ushort* __restrict__ WTh, ushort* __restrict__ WTt) {
    const float* src = blockIdx.z ? Wt : Wh;
    ushort* dst = blockIdx.z ? WTt : WTh;
    int r0 = blockIdx.x * 32, c0 = blockIdx.y * 32;
    int tx = threadIdx.x & 31, ty = threadIdx.x >> 5;
    __shared__ float tile[32][33];
    for (int p = 0; p < 4; p++) {
        int r = r0 + ty + p * 8, c = c0 + tx;
        tile[ty + p * 8][tx] = src[(size_t)r * cEMB + c];
    }
    __syncthreads();
    for (int p = 0; p < 4; p++) {
        int c = c0 + ty + p * 8, r = r0 + tx;
        dst[(size_t)c * (2 * cH) + r] = f2bf(tile[tx][ty + p * 8]);
    }
}

// ---------------------------------------------------------------------------
// Build fragment-ordered bilinear weights:
// Wf[si][f][lane][8] bf16,  si = 0..767, f = khalf*8+ct,
// element = W[(si*64 + j)][c], j = khalf*32 + (lane>>4)*8 + jj, c = ct*16 + (lane&15)
__global__ void wf_build_k(const float* __restrict__ W, ushort* __restrict__ Wf) {
    const int si = blockIdx.x;
    const int tid = threadIdx.x;
    __shared__ ushort sWb[64 * 136];
    for (int idx = tid; idx < 64 * 128; idx += 256) {
        int r = idx >> 7, c = idx & 127;
        float v = (c < cC) ? W[((size_t)si * 64 + r) * cC + c] : 0.f;
        sWb[r * 136 + c] = f2bf(v);
    }
    __syncthreads();
#pragma unroll
    for (int p = 0; p < 4; p++) {
        int e = tid + p * 256;          // 0..1023
        int f = e >> 6, lane = e & 63;
        int g = lane >> 4, col = lane & 15;
        int khalf = f >> 3, ct = f & 7;
        int jb = khalf * 32 + g * 8;
        int c = ct * 16 + col;
        short8 v;
#pragma unroll
        for (int jj = 0; jj < 8; jj++) v[jj] = (short)sWb[(jb + jj) * 136 + c];
        *(short8*)&Wf[(((size_t)si * 16 + f) * 64 + lane) * 8] = v;
    }
}

// ---------------------------------------------------------------------------
// Kernel 1: per-(b,e) logsumexp pooling of ent_lhs; writes bf16
__global__ void ent_pool_k(const float* __restrict__ ent_lhs, const int* __restrict__ ids,
                           ushort* __restrict__ ent_emb, int* __restrict__ counts) {
    int e = blockIdx.x, b = blockIdx.y;
    __shared__ int sid[cM];
    int tid = threadIdx.x;
    if (tid < cM) sid[tid] = ids[b * cM + tid];
    __syncthreads();
    int cnt = 0;
    for (int m = 0; m < cM; m++) cnt += (sid[m] == e) ? 1 : 0;
    if (tid == 0) counts[b * cE + e] = cnt;
    for (int h = tid; h < cH; h += 256) {
        float mx = -1e30f;
        for (int m = 0; m < cM; m++)
            if (sid[m] == e) mx = fmaxf(mx, ent_lhs[(size_t)(b * cM + m) * cH + h]);
        float s = 0.f;
        for (int m = 0; m < cM; m++)
            if (sid[m] == e) s += __expf(ent_lhs[(size_t)(b * cM + m) * cH + h] - mx);
        ent_emb[(size_t)(b * cE + e) * cH + h] = f2bf((cnt > 0) ? (mx + __logf(s)) : 0.f);
    }
}

// ---------------------------------------------------------------------------
// Kernel 2: ent_attn[b][e][a][l] (bf16) = segment-mean of attn
__global__ void ent_attn_k(const float* __restrict__ attn, const int* __restrict__ ids,
                           const int* __restrict__ counts, ushort* __restrict__ ent_attn) {
    int ba = blockIdx.x;
    int b = ba / cA, a = ba % cA;
    int tid = threadIdx.x;
    int l = blockIdx.y * 256 + tid;
    __shared__ int sid[cM];
    __shared__ int scnt[cE];
    __shared__ float sacc[256 * 33];
    if (tid < cM) sid[tid] = ids[b * cM + tid];
    if (tid < cE) scnt[tid] = counts[b * cE + tid];
    float* acc = &sacc[tid * 33];
    for (int e2 = 0; e2 < cE; e2++) acc[e2] = 0.f;
    __syncthreads();
    const float* ap = attn + ((size_t)(b * cA + a) * cM) * cL + l;
    for (int m = 0; m < cM; m++) acc[sid[m]] += ap[(size_t)m * cL];
    for (int e2 = 0; e2 < cE; e2++) {
        ent_attn[((size_t)(b * cE + e2) * cA + a) * cL + l] =
            f2bf(acc[e2] / (float)max(scnt[e2], 1));
    }
}

// ---------------------------------------------------------------------------
// Kernel 3: w[b][r][l] = mean_a ha*ta, normalized over l.
// Vectorized: each thread owns 4 consecutive l (ushort4 loads).
__global__ void w_k(const ushort* __restrict__ ent_attn, const int* __restrict__ hts,
                    ushort* __restrict__ w) {
    int nr = blockIdx.x;
    int b = nr / cR;
    int he = hts[nr * 2 + 0], te = hts[nr * 2 + 1];
    int tid = threadIdx.x;
    int l0 = tid * 4;
    const ushort* ha = ent_attn + ((size_t)(b * cE + he) * cA) * cL + l0;
    const ushort* ta = ent_attn + ((size_t)(b * cE + te) * cA) * cL + l0;
    float v[4] = {0.f, 0.f, 0.f, 0.f};
#pragma unroll
    for (int a = 0; a < cA; a++) {
        ushort4v hv = *(const ushort4v*)&ha[(size_t)a * cL];
        ushort4v tv = *(const ushort4v*)&ta[(size_t)a * cL];
#pragma unroll
        for (int i = 0; i < 4; i++) v[i] += bf2f(hv[i]) * bf2f(tv[i]);
    }
    float psum = 0.f;
#pragma unroll
    for (int i = 0; i < 4; i++) { v[i] *= (1.0f / cA); psum += v[i]; }
    for (int off = 32; off > 0; off >>= 1) psum += __shfl_down(psum, off, 64);
    __shared__ float red[4];
    if ((tid & 63) == 0) red[tid >> 6] = psum;
    __syncthreads();
    float tot = red[0] + red[1] + red[2] + red[3];
    float inv = 1.0f / (tot + 1e-5f);
    ushort4v o;
#pragma unroll
    for (int i = 0; i < 4; i++) o[i] = f2bf(v[i] * inv);
    *(ushort4v*)&w[(size_t)nr * cL + l0] = o;
}

// ---------------------------------------------------------------------------
// Kernel 4: rel MFMA GEMM: rel[n][h] = sum_l w[n][l] * seqT[b][h][l]
__global__ __launch_bounds__(256) void
rel_mfma_k(const ushort* __restrict__ wbf, const ushort* __restrict__ seqT,
           ushort* __restrict__ relbf) {
    const int b = blockIdx.z;
    const int r0 = blockIdx.x * 128, h0 = blockIdx.y * 64;
    const int tid = threadIdx.x, lane = tid & 63, wv = tid >> 6;
    const int col = lane & 15, g = lane >> 4;

    __shared__ ushort sA[128 * 72];
    __shared__ ushort sB[64 * 72];

    float4v acc[2][4];
#pragma unroll
    for (int mt = 0; mt < 2; mt++)
#pragma unroll
        for (int ct = 0; ct < 4; ct++) acc[mt][ct] = (float4v){0.f, 0.f, 0.f, 0.f};

    for (int kt = 0; kt < cL; kt += 64) {
#pragma unroll
        for (int p = 0; p < 4; p++) {
            int t = tid + p * 256;
            int row = t >> 3, seg = t & 7;
            int r = min(r0 + row, cR - 1);
            *(short8*)&sA[row * 72 + seg * 8] =
                *(const short8*)&wbf[((size_t)b * cR + r) * cL + kt + seg * 8];
        }
#pragma unroll
        for (int p = 0; p < 2; p++) {
            int t = tid + p * 256;
            int c = t >> 3, seg = t & 7;
            *(short8*)&sB[c * 72 + seg * 8] =
                *(const short8*)&seqT[((size_t)b * cH + h0 + c) * cL + kt + seg * 8];
        }
        __syncthreads();
        const int wrow = wv * 32;
#pragma unroll
        for (int k0 = 0; k0 < 64; k0 += 32) {
            short8 a0 = *(const short8*)&sA[(wrow + col) * 72 + k0 + g * 8];
            short8 a1 = *(const short8*)&sA[(wrow + 16 + col) * 72 + k0 + g * 8];
#pragma unroll
            for (int ct = 0; ct < 4; ct++) {
                short8 bf = *(const short8*)&sB[(ct * 16 + col) * 72 + k0 + g * 8];
                acc[0][ct] = __builtin_amdgcn_mfma_f32_16x16x32_bf16(a0, bf, acc[0][ct], 0, 0, 0);
                acc[1][ct] = __builtin_amdgcn_mfma_f32_16x16x32_bf16(a1, bf, acc[1][ct], 0, 0, 0);
            }
        }
        __syncthreads();
    }
#pragma unroll
    for (int mt = 0; mt < 2; mt++) {
#pragma unroll
        for (int ct = 0; ct < 4; ct++) {
            int h = h0 + ct * 16 + col;
            int rowb = r0 + wv * 32 + mt * 16 + g * 4;
#pragma unroll
            for (int reg = 0; reg < 4; reg++) {
                int r = rowb + reg;
                if (r < cR)
                    relbf[((size_t)b * cR + r) * cH + h] = f2bf(acc[mt][ct][reg]);
            }
        }
    }
}

// ---------------------------------------------------------------------------
// Kernel 5: projection MFMA GEMM, head+tail fused (blockIdx.z = sel).
// 64x64 tiles -> grid (62, 12, 2) = 1488 blocks. Each wave: 16 rows x 64 cols.
__global__ __launch_bounds__(256) void
proj_mfma_k(const ushort* __restrict__ ent_bf, const ushort* __restrict__ relbf,
            const int* __restrict__ hts,
            const ushort* __restrict__ WTh, const ushort* __restrict__ WTt,
            const float* __restrict__ head_b, const float* __restrict__ tail_b,
            ushort* __restrict__ hsp, ushort* __restrict__ tsp) {
    const int sel = blockIdx.z;
    const ushort* WTp = sel ? WTt : WTh;
    const float* bias = sel ? tail_b : head_b;
    ushort* outp = sel ? tsp : hsp;

    const int n0 = blockIdx.x * 64, e0 = blockIdx.y * 64;
    const int tid = threadIdx.x, lane = tid & 63, wv = tid >> 6;
    const int col = lane & 15, g = lane >> 4;

    __shared__ int sbase[64];
    __shared__ ushort sA[64 * 72];
    __shared__ ushort sB[64 * 72];

    if (tid < 64) {
        int n = n0 + tid, bb = n / cR;
        sbase[tid] = (bb * cE + hts[n * 2 + sel]) * cH;
    }
    __syncthreads();

    float4v acc[4];
#pragma unroll
    for (int ct = 0; ct < 4; ct++) acc[ct] = (float4v){0.f, 0.f, 0.f, 0.f};

    for (int kt = 0; kt < 2 * cH; kt += 64) {
        const bool first = kt < cH;
#pragma unroll
        for (int p = 0; p < 2; p++) {
            int t = tid + p * 256;
            int row = t >> 3, seg = t & 7;
            const ushort* src = first
                ? &ent_bf[(size_t)sbase[row] + kt + seg * 8]
                : &relbf[(size_t)(n0 + row) * cH + (kt - cH) + seg * 8];
            *(short8*)&sA[row * 72 + seg * 8] = *(const short8*)src;
        }
#pragma unroll
        for (int p = 0; p < 2; p++) {
            int t = tid + p * 256;
            int c = t >> 3, seg = t & 7;
            *(short8*)&sB[c * 72 + seg * 8] =
                *(const short8*)&WTp[(size_t)(e0 + c) * (2 * cH) + kt + seg * 8];
        }
        __syncthreads();
        const int wrow = wv * 16;
#pragma unroll
        for (int k0 = 0; k0 < 64; k0 += 32) {
            short8 a0 = *(const short8*)&sA[(wrow + col) * 72 + k0 + g * 8];
#pragma unroll
            for (int ct = 0; ct < 4; ct++) {
                short8 bf = *(const short8*)&sB[(ct * 16 + col) * 72 + k0 + g * 8];
                acc[ct] = __builtin_amdgcn_mfma_f32_16x16x32_bf16(a0, bf, acc[ct], 0, 0, 0);
            }
        }
        __syncthreads();
    }
#pragma unroll
    for (int ct = 0; ct < 4; ct++) {
        int e = e0 + ct * 16 + col;
        float bv = bias[e];
        int rowb = n0 + wv * 16 + g * 4;
#pragma unroll
        for (int reg = 0; reg < 4; reg++)
            outp[(size_t)(rowb + reg) * cEMB + e] = f2bf(tanhf(acc[ct][reg] + bv));
    }
}

// ---------------------------------------------------------------------------
// Kernel 6a: out init with bias
__global__ void out_init_k(const float* __restrict__ bil_b, float* __restrict__ out) {
    int idx = blockIdx.x * 256 + threadIdx.x;
    if (idx < cN * cC) out[idx] = bil_b[idx % cC];
}

// ---------------------------------------------------------------------------
// Kernel 6b: bilinear v5 — same register structure as the verified 97 µs v3
// (VGPR=128, no spill), but 48 i-slices of 16 i's -> grid (48, 31) = 1488
// blocks (~5.8/CU) so the 4-blocks/CU VGPR budget is actually usable.
// W L2 traffic unchanged (381 MB); atomics double (48 adds/output).
// 48 % 8 == 0 keeps islice%8 XCD affinity -> 1.5 MB Wf/XCD, L2-resident.
__global__ __launch_bounds__(256, 2) void
bil_mfma5_k(const ushort* __restrict__ hsp, const ushort* __restrict__ tsp,
            const ushort* __restrict__ Wf, float* __restrict__ out) {
    const int islice = blockIdx.x;       // 0..47 (16 i's each)
    const int n0 = blockIdx.y * 128;
    const int kb = islice >> 2;          // ts column block (4 slices per kb)
    const int tid = threadIdx.x;
    const int lane = tid & 63, wv = tid >> 6;
    const int col = lane & 15, g = lane >> 4;
    const int rh = wv >> 1, cth = wv & 1;

    __shared__ float sHs[16 * 132];      // [i][row]

    // stage hs tile -> f32 LDS, transposed (16 i x 128 rows)
    for (int idx = tid; idx < 256; idx += 256) {
        int row = idx & 127, seg = idx >> 7;   // seg 0..1
        short8 v = *(const short8*)&hsp[(size_t)(n0 + row) * cEMB + islice * 16 + seg * 8];
#pragma unroll
        for (int jj = 0; jj < 8; jj++)
            sHs[(seg * 8 + jj) * 132 + row] = bf2f((ushort)v[jj]);
    }

    // ts A-fragments (held in registers for all iterations)
    short8 tsA[4][2];
#pragma unroll
    for (int mt = 0; mt < 4; mt++)
#pragma unroll
        for (int kh = 0; kh < 2; kh++)
            tsA[mt][kh] = *(const short8*)
                &tsp[(size_t)(n0 + rh * 64 + mt * 16 + col) * cEMB + kb * 64 + kh * 32 + g * 8];

    float4v acc[4][4];
#pragma unroll
    for (int mt = 0; mt < 4; mt++)
#pragma unroll
        for (int ct = 0; ct < 4; ct++) acc[mt][ct] = (float4v){0.f, 0.f, 0.f, 0.f};

    const ushort* WfS = Wf + (size_t)islice * 16 * 8192;

#define WFRAG(i, ctl, kh) \
    (*(const short8*)&WfS[(((size_t)(i) * 16 + (kh) * 8 + cth * 4 + (ctl)) * 64 + lane) * 8])

    short8 w0[8], w1[8];
#pragma unroll
    for (int ctl = 0; ctl < 4; ctl++) {
        w0[ctl * 2 + 0] = WFRAG(0, ctl, 0);
        w0[ctl * 2 + 1] = WFRAG(0, ctl, 1);
    }
    __syncthreads();  // hs staged (the only barrier)

    for (int i = 0; i < 16; i += 2) {
        // prefetch i+1 while computing i
#pragma unroll
        for (int ctl = 0; ctl < 4; ctl++) {
            w1[ctl * 2 + 0] = WFRAG(i + 1, ctl, 0);
            w1[ctl * 2 + 1] = WFRAG(i + 1, ctl, 1);
        }
        {
            float4v hsv[4];
#pragma unroll
            for (int mt = 0; mt < 4; mt++)
                hsv[mt] = *(const float4v*)&sHs[i * 132 + rh * 64 + mt * 16 + g * 4];
#pragma unroll
            for (int ctl = 0; ctl < 4; ctl++) {
#pragma unroll
                for (int mt = 0; mt < 4; mt++) {
                    float4v P = (float4v){0.f, 0.f, 0.f, 0.f};
                    P = __builtin_amdgcn_mfma_f32_16x16x32_bf16(tsA[mt][0], w0[ctl * 2 + 0], P, 0, 0, 0);
                    P = __builtin_amdgcn_mfma_f32_16x16x32_bf16(tsA[mt][1], w0[ctl * 2 + 1], P, 0, 0, 0);
                    acc[mt][ctl] += hsv[mt] * P;
                }
            }
        }
        // prefetch i+2 while computing i+1
        if (i + 2 < 16) {
#pragma unroll
            for (int ctl = 0; ctl < 4; ctl++) {
                w0[ctl * 2 + 0] = WFRAG(i + 2, ctl, 0);
                w0[ctl * 2 + 1] = WFRAG(i + 2, ctl, 1);
            }
        }
        {
            float4v hsv[4];
#pragma unroll
            for (int mt = 0; mt < 4; mt++)
                hsv[mt] = *(const float4v*)&sHs[(i + 1) * 132 + rh * 64 + mt * 16 + g * 4];
#pragma unroll
            for (int ctl = 0; ctl < 4; ctl++) {
#pragma unroll
                for (int mt = 0; mt < 4; mt++) {
                    float4v P = (float4v){0.f, 0.f, 0.f, 0.f};
                    P = __builtin_amdgcn_mfma_f32_16x16x32_bf16(tsA[mt][0], w1[ctl * 2 + 0], P, 0, 0, 0);
                    P = __builtin_amdgcn_mfma_f32_16x16x32_bf16(tsA[mt][1], w1[ctl * 2 + 1], P, 0, 0, 0);
                    acc[mt][ctl] += hsv[mt] * P;
                }
            }
        }
    }
#undef WFRAG

    // epilogue: atomic combine over 48 slices
#pragma unroll
    for (int mt = 0; mt < 4; mt++) {
#pragma unroll
        for (int ctl = 0; ctl < 4; ctl++) {
            int c = (cth * 4 + ctl) * 16 + col;
            if (c < cC) {
                int rowb = n0 + rh * 64 + mt * 16 + g * 4;
#pragma unroll
                for (int reg = 0; reg < 4; reg++)
                    atomicAdd(&out[(size_t)(rowb + reg) * cC + c], acc[mt][ctl][reg]);
            }
        }
    }
}

// ---------------------------------------------------------------------------
extern "C" void kernel_launch(void* const* d_in, const int* in_sizes, int n_in,
                              void* d_out, int out_size, void* d_ws, size_t ws_size,
                              hipStream_t stream) {
    const float* seq_lhs  = (const float*)d_in[0];
    const float* ent_lhs  = (const float*)d_in[1];
    const float* attn     = (const float*)d_in[2];
    const int*   ids      = (const int*)d_in[3];
    const int*   hts      = (const int*)d_in[4];
    const float* head_W   = (const float*)d_in[5];
    const float* head_b   = (const float*)d_in[6];
    const float* tail_W   = (const float*)d_in[7];
    const float* tail_b   = (const float*)d_in[8];
    const float* bil_W    = (const float*)d_in[9];
    const float* bil_b    = (const float*)d_in[10];
    float* out = (float*)d_out;

    // workspace layout (byte offsets, 256B-aligned)
    char* ws = (char*)d_ws;
    int*    counts   = (int*)(ws + 0);             // 512 B
    ushort* ent_bf   = (ushort*)(ws + 512);        // 262144 B
    ushort* ent_attn = (ushort*)(ws + 262656);     // bf16, 4194304 B
    ushort* wbuf     = (ushort*)(ws + 4456960);    // 8126464 B
    ushort* relbf    = (ushort*)(ws + 12583424);   // 8126464 B
    ushort* hsp      = (ushort*)(ws + 20709888);   // 6094848 B
    ushort* tsp      = (ushort*)(ws + 26804736);   // 6094848 B
    ushort* Wf       = (ushort*)(ws + 32899584);   // 12582912 B
    ushort* WTh      = (ushort*)(ws + 45482496);   // 3145728 B
    ushort* WTt      = (ushort*)(ws + 48628224);   // 3145728 B
    ushort* seqT     = (ushort*)(ws + 51773952);   // 8388608 B  (end 60162560)

    hipLaunchKernelGGL(wf_build_k, dim3(768), dim3(256), 0, stream, bil_W, Wf);
    hipLaunchKernelGGL(tr_ht_k, dim3(64, 24, 2), dim3(256), 0, stream,
                       head_W, tail_W, WTh, WTt);
    hipLaunchKernelGGL(tr_bf16_k, dim3(32, 32, cB), dim3(256), 0, stream,
                       seq_lhs, seqT, cL, cH, cH);

    hipLaunchKernelGGL(ent_pool_k, dim3(cE, cB), dim3(256), 0, stream,
                       ent_lhs, ids, ent_bf, counts);
    hipLaunchKernelGGL(ent_attn_k, dim3(cB * cA, cL / 256), dim3(256), 0, stream,
                       attn, ids, counts, ent_attn);
    hipLaunchKernelGGL(w_k, dim3(cN), dim3(256), 0, stream,
                       ent_attn, hts, wbuf);
    hipLaunchKernelGGL(rel_mfma_k, dim3(8, 16, cB), dim3(256), 0, stream,
                       wbuf, seqT, relbf);
    hipLaunchKernelGGL(proj_mfma_k, dim3(cN / 64, cEMB / 64, 2), dim3(256), 0, stream,
                       ent_bf, relbf, hts, WTh, WTt, head_b, tail_b, hsp, tsp);
    hipLaunchKernelGGL(out_init_k, dim3((cN * cC + 255) / 256), dim3(256), 0, stream,
                       bil_b, out);
    hipLaunchKernelGGL(bil_mfma5_k, dim3(48, cN / 128), dim3(256), 0, stream,
                       hsp, tsp, Wf, out);
}

// Round 9
// 469.820 us; speedup vs baseline: 1.0364x; 1.0364x over previous
//
#include <hip/hip_runtime.h>
#include <hip/hip_bf16.h>
#include <math.h>

// Problem constants
constexpr int cB   = 4;
constexpr int cL   = 1024;
constexpr int cH   = 1024;
constexpr int cA   = 16;
constexpr int cM   = 128;
constexpr int cE   = 32;
constexpr int cR   = 992;
constexpr int cEMB = 768;
constexpr int cC   = 97;
constexpr int cN   = cB * cR;   // 3968

typedef unsigned short ushort;
typedef __attribute__((ext_vector_type(4))) unsigned short ushort4v;
typedef __attribute__((ext_vector_type(8))) short short8;
typedef __attribute__((ext_vector_type(4))) float float4v;

static __device__ inline float bf2f(ushort u) {
    unsigned v = ((unsigned)u) << 16;
    float f;
    __builtin_memcpy(&f, &v, 4);
    return f;
}
static __device__ inline ushort f2bf(float f) {
    unsigned u;
    __builtin_memcpy(&u, &f, 4);
    unsigned r = (u + 0x7FFFu + ((u >> 16) & 1u)) >> 16;
    return (ushort)r;
}

// true-async global->LDS, 16B per lane (wave-uniform base + lane*16)
static __device__ inline void gld_lds16(void* lds, const void* gsrc) {
    __builtin_amdgcn_global_load_lds(
        (const __attribute__((address_space(1))) unsigned int*)gsrc,
        (__attribute__((address_space(3))) unsigned int*)lds, 16, 0, 0);
}

// ---------------------------------------------------------------------------
// Generic transpose f32 -> bf16: src[z][R][C] -> dst[z][Cp][R], zero-pad c>=C
__global__ void tr_bf16_k(const float* __restrict__ src, ushort* __restrict__ dst,
                          int R, int C, int Cp) {
    int z = blockIdx.z;
    int r0 = blockIdx.x * 32, c0 = blockIdx.y * 32;
    int tx = threadIdx.x & 31, ty = threadIdx.x >> 5;  // ty 0..7
    __shared__ float tile[32][33];
    for (int p = 0; p < 4; p++) {
        int r = r0 + ty + p * 8, c = c0 + tx;
        tile[ty + p * 8][tx] = (r < R && c < C) ? src[((size_t)z * R + r) * C + c] : 0.f;
    }
    __syncthreads();
    for (int p = 0; p < 4; p++) {
        int c = c0 + ty + p * 8, r = r0 + tx;
        if (c < Cp && r < R)
            dst[((size_t)z * Cp + c) * R + r] = f2bf(tile[tx][ty + p * 8]);
    }
}

// Head+tail weight transpose in one launch (z selects which matrix)
__global__ void tr_ht_k(const float* __restrict__ Wh, const float* __restrict__ Wt,
                        ushort* __restrict__ WTh, ushort* __restrict__ WTt) {
    const float* src = blockIdx.z ? Wt : Wh;
    ushort* dst = blockIdx.z ? WTt : WTh;
    int r0 = blockIdx.x * 32, c0 = blockIdx.y * 32;
    int tx = threadIdx.x & 31, ty = threadIdx.x >> 5;
    __shared__ float tile[32][33];
    for (int p = 0; p < 4; p++) {
        int r = r0 + ty + p * 8, c = c0 + tx;
        tile[ty + p * 8][tx] = src[(size_t)r * cEMB + c];
    }
    __syncthreads();
    for (int p = 0; p < 4; p++) {
        int c = c0 + ty + p * 8, r = r0 + tx;
        dst[(size_t)c * (2 * cH) + r] = f2bf(tile[tx][ty + p * 8]);
    }
}

// ---------------------------------------------------------------------------
// Build fragment-ordered bilinear weights, 14 fragments per i (c-tiles 0..6
// only — tile 7 (c in [112,128)) is all-zero padding and is DROPPED):
// Wf[si][f'][lane][8] bf16, f' = kh*7 + ct (ct 0..6),
// element = W[(si*64 + j)][c], j = kh*32 + (lane>>4)*8 + jj, c = ct*16 + (lane&15)
__global__ void wf_build_k(const float* __restrict__ W, ushort* __restrict__ Wf) {
    const int si = blockIdx.x;
    const int tid = threadIdx.x;
    __shared__ ushort sWb[64 * 136];
    for (int idx = tid; idx < 64 * 128; idx += 256) {
        int r = idx >> 7, c = idx & 127;
        float v = (c < cC) ? W[((size_t)si * 64 + r) * cC + c] : 0.f;
        sWb[r * 136 + c] = f2bf(v);
    }
    __syncthreads();
#pragma unroll
    for (int p = 0; p < 4; p++) {
        int e = tid + p * 256;          // 0..1023, use 0..895
        if (e < 896) {
            int f = e >> 6, lane = e & 63;
            int g = lane >> 4, col = lane & 15;
            int kh = f / 7, ct = f % 7;
            int jb = kh * 32 + g * 8;
            int c = ct * 16 + col;
            short8 v;
#pragma unroll
            for (int jj = 0; jj < 8; jj++) v[jj] = (short)sWb[(jb + jj) * 136 + c];
            *(short8*)&Wf[((size_t)si * 14 + f) * 512 + lane * 8] = v;
        }
    }
}

// ---------------------------------------------------------------------------
// Kernel 1: per-(b,e) logsumexp pooling of ent_lhs; writes bf16
__global__ void ent_pool_k(const float* __restrict__ ent_lhs, const int* __restrict__ ids,
                           ushort* __restrict__ ent_emb, int* __restrict__ counts) {
    int e = blockIdx.x, b = blockIdx.y;
    __shared__ int sid[cM];
    int tid = threadIdx.x;
    if (tid < cM) sid[tid] = ids[b * cM + tid];
    __syncthreads();
    int cnt = 0;
    for (int m = 0; m < cM; m++) cnt += (sid[m] == e) ? 1 : 0;
    if (tid == 0) counts[b * cE + e] = cnt;
    for (int h = tid; h < cH; h += 256) {
        float mx = -1e30f;
        for (int m = 0; m < cM; m++)
            if (sid[m] == e) mx = fmaxf(mx, ent_lhs[(size_t)(b * cM + m) * cH + h]);
        float s = 0.f;
        for (int m = 0; m < cM; m++)
            if (sid[m] == e) s += __expf(ent_lhs[(size_t)(b * cM + m) * cH + h] - mx);
        ent_emb[(size_t)(b * cE + e) * cH + h] = f2bf((cnt > 0) ? (mx + __logf(s)) : 0.f);
    }
}

// ---------------------------------------------------------------------------
// Kernel 2: ent_attn[b][e][a][l] (bf16) = segment-mean of attn
__global__ void ent_attn_k(const float* __restrict__ attn, const int* __restrict__ ids,
                           const int* __restrict__ counts, ushort* __restrict__ ent_attn) {
    int ba = blockIdx.x;
    int b = ba / cA, a = ba % cA;
    int tid = threadIdx.x;
    int l = blockIdx.y * 256 + tid;
    __shared__ int sid[cM];
    __shared__ int scnt[cE];
    __shared__ float sacc[256 * 33];
    if (tid < cM) sid[tid] = ids[b * cM + tid];
    if (tid < cE) scnt[tid] = counts[b * cE + tid];
    float* acc = &sacc[tid * 33];
    for (int e2 = 0; e2 < cE; e2++) acc[e2] = 0.f;
    __syncthreads();
    const float* ap = attn + ((size_t)(b * cA + a) * cM) * cL + l;
    for (int m = 0; m < cM; m++) acc[sid[m]] += ap[(size_t)m * cL];
    for (int e2 = 0; e2 < cE; e2++) {
        ent_attn[((size_t)(b * cE + e2) * cA + a) * cL + l] =
            f2bf(acc[e2] / (float)max(scnt[e2], 1));
    }
}

// ---------------------------------------------------------------------------
// Kernel 3: w[b][r][l] = mean_a ha*ta, normalized over l (ushort4 vectorized)
__global__ void w_k(const ushort* __restrict__ ent_attn, const int* __restrict__ hts,
                    ushort* __restrict__ w) {
    int nr = blockIdx.x;
    int b = nr / cR;
    int he = hts[nr * 2 + 0], te = hts[nr * 2 + 1];
    int tid = threadIdx.x;
    int l0 = tid * 4;
    const ushort* ha = ent_attn + ((size_t)(b * cE + he) * cA) * cL + l0;
    const ushort* ta = ent_attn + ((size_t)(b * cE + te) * cA) * cL + l0;
    float v[4] = {0.f, 0.f, 0.f, 0.f};
#pragma unroll
    for (int a = 0; a < cA; a++) {
        ushort4v hv = *(const ushort4v*)&ha[(size_t)a * cL];
        ushort4v tv = *(const ushort4v*)&ta[(size_t)a * cL];
#pragma unroll
        for (int i = 0; i < 4; i++) v[i] += bf2f(hv[i]) * bf2f(tv[i]);
    }
    float psum = 0.f;
#pragma unroll
    for (int i = 0; i < 4; i++) { v[i] *= (1.0f / cA); psum += v[i]; }
    for (int off = 32; off > 0; off >>= 1) psum += __shfl_down(psum, off, 64);
    __shared__ float red[4];
    if ((tid & 63) == 0) red[tid >> 6] = psum;
    __syncthreads();
    float tot = red[0] + red[1] + red[2] + red[3];
    float inv = 1.0f / (tot + 1e-5f);
    ushort4v o;
#pragma unroll
    for (int i = 0; i < 4; i++) o[i] = f2bf(v[i] * inv);
    *(ushort4v*)&w[(size_t)nr * cL + l0] = o;
}

// ---------------------------------------------------------------------------
// Kernel 4: rel MFMA GEMM: rel[n][h] = sum_l w[n][l] * seqT[b][h][l]
__global__ __launch_bounds__(256) void
rel_mfma_k(const ushort* __restrict__ wbf, const ushort* __restrict__ seqT,
           ushort* __restrict__ relbf) {
    const int b = blockIdx.z;
    const int r0 = blockIdx.x * 128, h0 = blockIdx.y * 64;
    const int tid = threadIdx.x, lane = tid & 63, wv = tid >> 6;
    const int col = lane & 15, g = lane >> 4;

    __shared__ ushort sA[128 * 72];
    __shared__ ushort sB[64 * 72];

    float4v acc[2][4];
#pragma unroll
    for (int mt = 0; mt < 2; mt++)
#pragma unroll
        for (int ct = 0; ct < 4; ct++) acc[mt][ct] = (float4v){0.f, 0.f, 0.f, 0.f};

    for (int kt = 0; kt < cL; kt += 64) {
#pragma unroll
        for (int p = 0; p < 4; p++) {
            int t = tid + p * 256;
            int row = t >> 3, seg = t & 7;
            int r = min(r0 + row, cR - 1);
            *(short8*)&sA[row * 72 + seg * 8] =
                *(const short8*)&wbf[((size_t)b * cR + r) * cL + kt + seg * 8];
        }
#pragma unroll
        for (int p = 0; p < 2; p++) {
            int t = tid + p * 256;
            int c = t >> 3, seg = t & 7;
            *(short8*)&sB[c * 72 + seg * 8] =
                *(const short8*)&seqT[((size_t)b * cH + h0 + c) * cL + kt + seg * 8];
        }
        __syncthreads();
        const int wrow = wv * 32;
#pragma unroll
        for (int k0 = 0; k0 < 64; k0 += 32) {
            short8 a0 = *(const short8*)&sA[(wrow + col) * 72 + k0 + g * 8];
            short8 a1 = *(const short8*)&sA[(wrow + 16 + col) * 72 + k0 + g * 8];
#pragma unroll
            for (int ct = 0; ct < 4; ct++) {
                short8 bf = *(const short8*)&sB[(ct * 16 + col) * 72 + k0 + g * 8];
                acc[0][ct] = __builtin_amdgcn_mfma_f32_16x16x32_bf16(a0, bf, acc[0][ct], 0, 0, 0);
                acc[1][ct] = __builtin_amdgcn_mfma_f32_16x16x32_bf16(a1, bf, acc[1][ct], 0, 0, 0);
            }
        }
        __syncthreads();
    }
#pragma unroll
    for (int mt = 0; mt < 2; mt++) {
#pragma unroll
        for (int ct = 0; ct < 4; ct++) {
            int h = h0 + ct * 16 + col;
            int rowb = r0 + wv * 32 + mt * 16 + g * 4;
#pragma unroll
            for (int reg = 0; reg < 4; reg++) {
                int r = rowb + reg;
                if (r < cR)
                    relbf[((size_t)b * cR + r) * cH + h] = f2bf(acc[mt][ct][reg]);
            }
        }
    }
}

// ---------------------------------------------------------------------------
// Kernel 5: projection MFMA GEMM, head+tail fused (blockIdx.z = sel).
__global__ __launch_bounds__(256) void
proj_mfma_k(const ushort* __restrict__ ent_bf, const ushort* __restrict__ relbf,
            const int* __restrict__ hts,
            const ushort* __restrict__ WTh, const ushort* __restrict__ WTt,
            const float* __restrict__ head_b, const float* __restrict__ tail_b,
            ushort* __restrict__ hsp, ushort* __restrict__ tsp) {
    const int sel = blockIdx.z;
    const ushort* WTp = sel ? WTt : WTh;
    const float* bias = sel ? tail_b : head_b;
    ushort* outp = sel ? tsp : hsp;

    const int n0 = blockIdx.x * 64, e0 = blockIdx.y * 64;
    const int tid = threadIdx.x, lane = tid & 63, wv = tid >> 6;
    const int col = lane & 15, g = lane >> 4;

    __shared__ int sbase[64];
    __shared__ ushort sA[64 * 72];
    __shared__ ushort sB[64 * 72];

    if (tid < 64) {
        int n = n0 + tid, bb = n / cR;
        sbase[tid] = (bb * cE + hts[n * 2 + sel]) * cH;
    }
    __syncthreads();

    float4v acc[4];
#pragma unroll
    for (int ct = 0; ct < 4; ct++) acc[ct] = (float4v){0.f, 0.f, 0.f, 0.f};

    for (int kt = 0; kt < 2 * cH; kt += 64) {
        const bool first = kt < cH;
#pragma unroll
        for (int p = 0; p < 2; p++) {
            int t = tid + p * 256;
            int row = t >> 3, seg = t & 7;
            const ushort* src = first
                ? &ent_bf[(size_t)sbase[row] + kt + seg * 8]
                : &relbf[(size_t)(n0 + row) * cH + (kt - cH) + seg * 8];
            *(short8*)&sA[row * 72 + seg * 8] = *(const short8*)src;
        }
#pragma unroll
        for (int p = 0; p < 2; p++) {
            int t = tid + p * 256;
            int c = t >> 3, seg = t & 7;
            *(short8*)&sB[c * 72 + seg * 8] =
                *(const short8*)&WTp[(size_t)(e0 + c) * (2 * cH) + kt + seg * 8];
        }
        __syncthreads();
        const int wrow = wv * 16;
#pragma unroll
        for (int k0 = 0; k0 < 64; k0 += 32) {
            short8 a0 = *(const short8*)&sA[(wrow + col) * 72 + k0 + g * 8];
#pragma unroll
            for (int ct = 0; ct < 4; ct++) {
                short8 bf = *(const short8*)&sB[(ct * 16 + col) * 72 + k0 + g * 8];
                acc[ct] = __builtin_amdgcn_mfma_f32_16x16x32_bf16(a0, bf, acc[ct], 0, 0, 0);
            }
        }
        __syncthreads();
    }
#pragma unroll
    for (int ct = 0; ct < 4; ct++) {
        int e = e0 + ct * 16 + col;
        float bv = bias[e];
        int rowb = n0 + wv * 16 + g * 4;
#pragma unroll
        for (int reg = 0; reg < 4; reg++)
            outp[(size_t)(rowb + reg) * cEMB + e] = f2bf(tanhf(acc[ct][reg] + bv));
    }
}

// ---------------------------------------------------------------------------
// Kernel 6a: out init with bias
__global__ void out_init_k(const float* __restrict__ bil_b, float* __restrict__ out) {
    int idx = blockIdx.x * 256 + threadIdx.x;
    if (idx < cN * cC) out[idx] = bil_b[idx % cC];
}

// ---------------------------------------------------------------------------
// Kernel 6b: bilinear v6 — W staged through LDS with TRUE async
// (global_load_lds w=16) double-buffer; the prefetch is structural, immune
// to register-allocator load sinking (the r5/r8 97 µs plateau cause).
// 14 c-fragments per i (padding tile dropped). Waves 2(row-half) x 2(c-part:
// ct 0-3 / 4-6). 128 rows x 32 i per block, grid (24, 31); islice%8 XCD
// affinity keeps Wf L2-resident. One barrier per i (m97 structure).
__global__ __launch_bounds__(256) void
bil_mfma6_k(const ushort* __restrict__ hsp, const ushort* __restrict__ tsp,
            const ushort* __restrict__ Wf, float* __restrict__ out) {
    const int islice = blockIdx.x;       // 0..23 (32 i's each)
    const int n0 = blockIdx.y * 128;
    const int kb = islice >> 1;          // ts column block
    const int tid = threadIdx.x;
    const int lane = tid & 63, wv = tid >> 6;
    const int col = lane & 15, g = lane >> 4;
    const int rh = wv >> 1, cth = wv & 1;

    __shared__ ushort sW[2][14 * 512];   // 14 frags x 64 lanes x 8 shorts, x2 buf
    __shared__ float sHs[32 * 132];      // [i][row]

    // stage hs tile -> f32 LDS, transposed
    for (int idx = tid; idx < 512; idx += 256) {
        int row = idx & 127, seg = idx >> 7;
        short8 v = *(const short8*)&hsp[(size_t)(n0 + row) * cEMB + islice * 32 + seg * 8];
#pragma unroll
        for (int jj = 0; jj < 8; jj++)
            sHs[(seg * 8 + jj) * 132 + row] = bf2f((ushort)v[jj]);
    }

    // ts A-fragments in registers (rows rh*64 + mt*16 + col)
    short8 tsA[4][2];
#pragma unroll
    for (int mt = 0; mt < 4; mt++)
#pragma unroll
        for (int kh = 0; kh < 2; kh++)
            tsA[mt][kh] = *(const short8*)
                &tsp[(size_t)(n0 + rh * 64 + mt * 16 + col) * cEMB + kb * 64 + kh * 32 + g * 8];

    float4v acc[4][4];
#pragma unroll
    for (int mt = 0; mt < 4; mt++)
#pragma unroll
        for (int ct = 0; ct < 4; ct++) acc[mt][ct] = (float4v){0.f, 0.f, 0.f, 0.f};

    const ushort* WfS = Wf + (size_t)islice * 32 * (14 * 512);

    // async-stage i=0 into buf 0 (896 x 16B = 14336 B)
#pragma unroll
    for (int p = 0; p < 4; p++) {
        int t = p * 256 + tid;
        if (t < 896) gld_lds16(&sW[0][t * 8], &WfS[(size_t)t * 8]);
    }
    __syncthreads();  // hs staged + stage(0) drained

    for (int i = 0; i < 32; i++) {
        const int buf = i & 1;
        // async prefetch of i+1 — in flight across the whole compute phase
        if (i + 1 < 32) {
            const ushort* src = WfS + (size_t)(i + 1) * (14 * 512);
#pragma unroll
            for (int p = 0; p < 4; p++) {
                int t = p * 256 + tid;
                if (t < 896) gld_lds16(&sW[buf ^ 1][t * 8], &src[(size_t)t * 8]);
            }
        }
        float4v hsv[4];
#pragma unroll
        for (int mt = 0; mt < 4; mt++)
            hsv[mt] = *(const float4v*)&sHs[i * 132 + rh * 64 + mt * 16 + g * 4];

        const ushort* sWb = sW[buf];
        auto do_ct = [&](int f0, int ctl) {
            short8 b0 = *(const short8*)&sWb[(size_t)f0 * 512 + lane * 8];
            short8 b1 = *(const short8*)&sWb[(size_t)(7 + f0) * 512 + lane * 8];
#pragma unroll
            for (int mt = 0; mt < 4; mt++) {
                float4v P = (float4v){0.f, 0.f, 0.f, 0.f};
                P = __builtin_amdgcn_mfma_f32_16x16x32_bf16(tsA[mt][0], b0, P, 0, 0, 0);
                P = __builtin_amdgcn_mfma_f32_16x16x32_bf16(tsA[mt][1], b1, P, 0, 0, 0);
                acc[mt][ctl] += hsv[mt] * P;
            }
        };
        if (cth == 0) {
            do_ct(0, 0); do_ct(1, 1); do_ct(2, 2); do_ct(3, 3);
        } else {
            do_ct(4, 0); do_ct(5, 1); do_ct(6, 2);
        }
        __syncthreads();  // drains prefetch(i+1); protects buf reuse
    }

    // epilogue: atomic combine over 24 slices
#pragma unroll
    for (int mt = 0; mt < 4; mt++) {
#pragma unroll
        for (int ctl = 0; ctl < 4; ctl++) {
            if (cth == 1 && ctl == 3) continue;
            int c = ((cth ? 4 : 0) + ctl) * 16 + col;
            if (c < cC) {
                int rowb = n0 + rh * 64 + mt * 16 + g * 4;
#pragma unroll
                for (int reg = 0; reg < 4; reg++)
                    atomicAdd(&out[(size_t)(rowb + reg) * cC + c], acc[mt][ctl][reg]);
            }
        }
    }
}

// ---------------------------------------------------------------------------
extern "C" void kernel_launch(void* const* d_in, const int* in_sizes, int n_in,
                              void* d_out, int out_size, void* d_ws, size_t ws_size,
                              hipStream_t stream) {
    const float* seq_lhs  = (const float*)d_in[0];
    const float* ent_lhs  = (const float*)d_in[1];
    const float* attn     = (const float*)d_in[2];
    const int*   ids      = (const int*)d_in[3];
    const int*   hts      = (const int*)d_in[4];
    const float* head_W   = (const float*)d_in[5];
    const float* head_b   = (const float*)d_in[6];
    const float* tail_W   = (const float*)d_in[7];
    const float* tail_b   = (const float*)d_in[8];
    const float* bil_W    = (const float*)d_in[9];
    const float* bil_b    = (const float*)d_in[10];
    float* out = (float*)d_out;

    // workspace layout (byte offsets, 256B-aligned)
    char* ws = (char*)d_ws;
    int*    counts   = (int*)(ws + 0);             // 512 B
    ushort* ent_bf   = (ushort*)(ws + 512);        // 262144 B
    ushort* ent_attn = (ushort*)(ws + 262656);     // bf16, 4194304 B
    ushort* wbuf     = (ushort*)(ws + 4456960);    // 8126464 B
    ushort* relbf    = (ushort*)(ws + 12583424);   // 8126464 B
    ushort* hsp      = (ushort*)(ws + 20709888);   // 6094848 B
    ushort* tsp      = (ushort*)(ws + 26804736);   // 6094848 B
    ushort* Wf       = (ushort*)(ws + 32899584);   // 768*14*512*2 = 11010048 B
    ushort* WTh      = (ushort*)(ws + 45482496);   // 3145728 B
    ushort* WTt      = (ushort*)(ws + 48628224);   // 3145728 B
    ushort* seqT     = (ushort*)(ws + 51773952);   // 8388608 B  (end 60162560)

    hipLaunchKernelGGL(wf_build_k, dim3(768), dim3(256), 0, stream, bil_W, Wf);
    hipLaunchKernelGGL(tr_ht_k, dim3(64, 24, 2), dim3(256), 0, stream,
                       head_W, tail_W, WTh, WTt);
    hipLaunchKernelGGL(tr_bf16_k, dim3(32, 32, cB), dim3(256), 0, stream,
                       seq_lhs, seqT, cL, cH, cH);

    hipLaunchKernelGGL(ent_pool_k, dim3(cE, cB), dim3(256), 0, stream,
                       ent_lhs, ids, ent_bf, counts);
    hipLaunchKernelGGL(ent_attn_k, dim3(cB * cA, cL / 256), dim3(256), 0, stream,
                       attn, ids, counts, ent_attn);
    hipLaunchKernelGGL(w_k, dim3(cN), dim3(256), 0, stream,
                       ent_attn, hts, wbuf);
    hipLaunchKernelGGL(rel_mfma_k, dim3(8, 16, cB), dim3(256), 0, stream,
                       wbuf, seqT, relbf);
    hipLaunchKernelGGL(proj_mfma_k, dim3(cN / 64, cEMB / 64, 2), dim3(256), 0, stream,
                       ent_bf, relbf, hts, WTh, WTt, head_b, tail_b, hsp, tsp);
    hipLaunchKernelGGL(out_init_k, dim3((cN * cC + 255) / 256), dim3(256), 0, stream,
                       bil_b, out);
    hipLaunchKernelGGL(bil_mfma6_k, dim3(24, cN / 128), dim3(256), 0, stream,
                       hsp, tsp, Wf, out);
}

// Round 10
// 412.234 us; speedup vs baseline: 1.1812x; 1.1397x over previous
//
#include <hip/hip_runtime.h>
#include <hip/hip_bf16.h>
#include <math.h>

// Problem constants
constexpr int cB   = 4;
constexpr int cL   = 1024;
constexpr int cH   = 1024;
constexpr int cA   = 16;
constexpr int cM   = 128;
constexpr int cE   = 32;
constexpr int cR   = 992;
constexpr int cEMB = 768;
constexpr int cC   = 97;
constexpr int cN   = cB * cR;   // 3968

typedef unsigned short ushort;
typedef __attribute__((ext_vector_type(4))) unsigned short ushort4v;
typedef __attribute__((ext_vector_type(8))) short short8;
typedef __attribute__((ext_vector_type(4))) float float4v;

static __device__ inline float bf2f(ushort u) {
    unsigned v = ((unsigned)u) << 16;
    float f;
    __builtin_memcpy(&f, &v, 4);
    return f;
}
static __device__ inline ushort f2bf(float f) {
    unsigned u;
    __builtin_memcpy(&u, &f, 4);
    unsigned r = (u + 0x7FFFu + ((u >> 16) & 1u)) >> 16;
    return (ushort)r;
}

// ---------------------------------------------------------------------------
// Generic transpose f32 -> bf16: src[z][R][C] -> dst[z][Cp][R], zero-pad c>=C
__global__ void tr_bf16_k(const float* __restrict__ src, ushort* __restrict__ dst,
                          int R, int C, int Cp) {
    int z = blockIdx.z;
    int r0 = blockIdx.x * 32, c0 = blockIdx.y * 32;
    int tx = threadIdx.x & 31, ty = threadIdx.x >> 5;  // ty 0..7
    __shared__ float tile[32][33];
    for (int p = 0; p < 4; p++) {
        int r = r0 + ty + p * 8, c = c0 + tx;
        tile[ty + p * 8][tx] = (r < R && c < C) ? src[((size_t)z * R + r) * C + c] : 0.f;
    }
    __syncthreads();
    for (int p = 0; p < 4; p++) {
        int c = c0 + ty + p * 8, r = r0 + tx;
        if (c < Cp && r < R)
            dst[((size_t)z * Cp + c) * R + r] = f2bf(tile[tx][ty + p * 8]);
    }
}

// Head+tail weight transpose in one launch (z selects which matrix)
__global__ void tr_ht_k(const float* __restrict__ Wh, const float* __restrict__ Wt,
                        ushort* __restrict__ WTh, ushort* __restrict__ WTt) {
    const float* src = blockIdx.z ? Wt : Wh;
    ushort* dst = blockIdx.z ? WTt : WTh;
    int r0 = blockIdx.x * 32, c0 = blockIdx.y * 32;
    int tx = threadIdx.x & 31, ty = threadIdx.x >> 5;
    __shared__ float tile[32][33];
    for (int p = 0; p < 4; p++) {
        int r = r0 + ty + p * 8, c = c0 + tx;
        tile[ty + p * 8][tx] = src[(size_t)r * cEMB + c];
    }
    __syncthreads();
    for (int p = 0; p < 4; p++) {
        int c = c0 + ty + p * 8, r = r0 + tx;
        dst[(size_t)c * (2 * cH) + r] = f2bf(tile[tx][ty + p * 8]);
    }
}

// ---------------------------------------------------------------------------
// Build fragment-ordered bilinear weights (16 frags per i, v3 layout):
// Wf[si][f][lane][8] bf16, f = khalf*8+ct,
// element = W[(si*64 + j)][c], j = khalf*32 + (lane>>4)*8 + jj, c = ct*16 + (lane&15)
__global__ void wf_build_k(const float* __restrict__ W, ushort* __restrict__ Wf) {
    const int si = blockIdx.x;
    const int tid = threadIdx.x;
    __shared__ ushort sWb[64 * 136];
    for (int idx = tid; idx < 64 * 128; idx += 256) {
        int r = idx >> 7, c = idx & 127;
        float v = (c < cC) ? W[((size_t)si * 64 + r) * cC + c] : 0.f;
        sWb[r * 136 + c] = f2bf(v);
    }
    __syncthreads();
#pragma unroll
    for (int p = 0; p < 4; p++) {
        int e = tid + p * 256;          // 0..1023
        int f = e >> 6, lane = e & 63;
        int g = lane >> 4, col = lane & 15;
        int khalf = f >> 3, ct = f & 7;
        int jb = khalf * 32 + g * 8;
        int c = ct * 16 + col;
        short8 v;
#pragma unroll
        for (int jj = 0; jj < 8; jj++) v[jj] = (short)sWb[(jb + jj) * 136 + c];
        *(short8*)&Wf[(((size_t)si * 16 + f) * 64 + lane) * 8] = v;
    }
}

// ---------------------------------------------------------------------------
// Kernel 1: per-(b,e) logsumexp pooling of ent_lhs; writes bf16.
// h split into 4 chunks -> grid (cE, cB, 4) = 512 blocks (was 128: 0.5/CU,
// latency-exposed).
__global__ void ent_pool_k(const float* __restrict__ ent_lhs, const int* __restrict__ ids,
                           ushort* __restrict__ ent_emb, int* __restrict__ counts) {
    int e = blockIdx.x, b = blockIdx.y;
    __shared__ int sid[cM];
    int tid = threadIdx.x;
    if (tid < cM) sid[tid] = ids[b * cM + tid];
    __syncthreads();
    int cnt = 0;
    for (int m = 0; m < cM; m++) cnt += (sid[m] == e) ? 1 : 0;
    if (blockIdx.z == 0 && tid == 0) counts[b * cE + e] = cnt;
    int h = blockIdx.z * 256 + tid;
    {
        float mx = -1e30f;
        for (int m = 0; m < cM; m++)
            if (sid[m] == e) mx = fmaxf(mx, ent_lhs[(size_t)(b * cM + m) * cH + h]);
        float s = 0.f;
        for (int m = 0; m < cM; m++)
            if (sid[m] == e) s += __expf(ent_lhs[(size_t)(b * cM + m) * cH + h] - mx);
        ent_emb[(size_t)(b * cE + e) * cH + h] = f2bf((cnt > 0) ? (mx + __logf(s)) : 0.f);
    }
}

// ---------------------------------------------------------------------------
// Kernel 2: ent_attn[b][e][a][l] (bf16) = segment-mean of attn
__global__ void ent_attn_k(const float* __restrict__ attn, const int* __restrict__ ids,
                           const int* __restrict__ counts, ushort* __restrict__ ent_attn) {
    int ba = blockIdx.x;
    int b = ba / cA, a = ba % cA;
    int tid = threadIdx.x;
    int l = blockIdx.y * 256 + tid;
    __shared__ int sid[cM];
    __shared__ int scnt[cE];
    __shared__ float sacc[256 * 33];
    if (tid < cM) sid[tid] = ids[b * cM + tid];
    if (tid < cE) scnt[tid] = counts[b * cE + tid];
    float* acc = &sacc[tid * 33];
    for (int e2 = 0; e2 < cE; e2++) acc[e2] = 0.f;
    __syncthreads();
    const float* ap = attn + ((size_t)(b * cA + a) * cM) * cL + l;
    for (int m = 0; m < cM; m++) acc[sid[m]] += ap[(size_t)m * cL];
    for (int e2 = 0; e2 < cE; e2++) {
        ent_attn[((size_t)(b * cE + e2) * cA + a) * cL + l] =
            f2bf(acc[e2] / (float)max(scnt[e2], 1));
    }
}

// ---------------------------------------------------------------------------
// Kernel 3: w[b][r][l] = mean_a ha*ta, normalized over l (ushort4 vectorized)
__global__ void w_k(const ushort* __restrict__ ent_attn, const int* __restrict__ hts,
                    ushort* __restrict__ w) {
    int nr = blockIdx.x;
    int b = nr / cR;
    int he = hts[nr * 2 + 0], te = hts[nr * 2 + 1];
    int tid = threadIdx.x;
    int l0 = tid * 4;
    const ushort* ha = ent_attn + ((size_t)(b * cE + he) * cA) * cL + l0;
    const ushort* ta = ent_attn + ((size_t)(b * cE + te) * cA) * cL + l0;
    float v[4] = {0.f, 0.f, 0.f, 0.f};
#pragma unroll
    for (int a = 0; a < cA; a++) {
        ushort4v hv = *(const ushort4v*)&ha[(size_t)a * cL];
        ushort4v tv = *(const ushort4v*)&ta[(size_t)a * cL];
#pragma unroll
        for (int i = 0; i < 4; i++) v[i] += bf2f(hv[i]) * bf2f(tv[i]);
    }
    float psum = 0.f;
#pragma unroll
    for (int i = 0; i < 4; i++) { v[i] *= (1.0f / cA); psum += v[i]; }
    for (int off = 32; off > 0; off >>= 1) psum += __shfl_down(psum, off, 64);
    __shared__ float red[4];
    if ((tid & 63) == 0) red[tid >> 6] = psum;
    __syncthreads();
    float tot = red[0] + red[1] + red[2] + red[3];
    float inv = 1.0f / (tot + 1e-5f);
    ushort4v o;
#pragma unroll
    for (int i = 0; i < 4; i++) o[i] = f2bf(v[i] * inv);
    *(ushort4v*)&w[(size_t)nr * cL + l0] = o;
}

// ---------------------------------------------------------------------------
// Kernel 4: rel MFMA GEMM: rel[n][h] = sum_l w[n][l] * seqT[b][h][l]
__global__ __launch_bounds__(256) void
rel_mfma_k(const ushort* __restrict__ wbf, const ushort* __restrict__ seqT,
           ushort* __restrict__ relbf) {
    const int b = blockIdx.z;
    const int r0 = blockIdx.x * 128, h0 = blockIdx.y * 64;
    const int tid = threadIdx.x, lane = tid & 63, wv = tid >> 6;
    const int col = lane & 15, g = lane >> 4;

    __shared__ ushort sA[128 * 72];
    __shared__ ushort sB[64 * 72];

    float4v acc[2][4];
#pragma unroll
    for (int mt = 0; mt < 2; mt++)
#pragma unroll
        for (int ct = 0; ct < 4; ct++) acc[mt][ct] = (float4v){0.f, 0.f, 0.f, 0.f};

    for (int kt = 0; kt < cL; kt += 64) {
#pragma unroll
        for (int p = 0; p < 4; p++) {
            int t = tid + p * 256;
            int row = t >> 3, seg = t & 7;
            int r = min(r0 + row, cR - 1);
            *(short8*)&sA[row * 72 + seg * 8] =
                *(const short8*)&wbf[((size_t)b * cR + r) * cL + kt + seg * 8];
        }
#pragma unroll
        for (int p = 0; p < 2; p++) {
            int t = tid + p * 256;
            int c = t >> 3, seg = t & 7;
            *(short8*)&sB[c * 72 + seg * 8] =
                *(const short8*)&seqT[((size_t)b * cH + h0 + c) * cL + kt + seg * 8];
        }
        __syncthreads();
        const int wrow = wv * 32;
#pragma unroll
        for (int k0 = 0; k0 < 64; k0 += 32) {
            short8 a0 = *(const short8*)&sA[(wrow + col) * 72 + k0 + g * 8];
            short8 a1 = *(const short8*)&sA[(wrow + 16 + col) * 72 + k0 + g * 8];
#pragma unroll
            for (int ct = 0; ct < 4; ct++) {
                short8 bf = *(const short8*)&sB[(ct * 16 + col) * 72 + k0 + g * 8];
                acc[0][ct] = __builtin_amdgcn_mfma_f32_16x16x32_bf16(a0, bf, acc[0][ct], 0, 0, 0);
                acc[1][ct] = __builtin_amdgcn_mfma_f32_16x16x32_bf16(a1, bf, acc[1][ct], 0, 0, 0);
            }
        }
        __syncthreads();
    }
#pragma unroll
    for (int mt = 0; mt < 2; mt++) {
#pragma unroll
        for (int ct = 0; ct < 4; ct++) {
            int h = h0 + ct * 16 + col;
            int rowb = r0 + wv * 32 + mt * 16 + g * 4;
#pragma unroll
            for (int reg = 0; reg < 4; reg++) {
                int r = rowb + reg;
                if (r < cR)
                    relbf[((size_t)b * cR + r) * cH + h] = f2bf(acc[mt][ct][reg]);
            }
        }
    }
}

// ---------------------------------------------------------------------------
// Kernel 5: projection MFMA GEMM, head+tail fused (blockIdx.z = sel).
__global__ __launch_bounds__(256) void
proj_mfma_k(const ushort* __restrict__ ent_bf, const ushort* __restrict__ relbf,
            const int* __restrict__ hts,
            const ushort* __restrict__ WTh, const ushort* __restrict__ WTt,
            const float* __restrict__ head_b, const float* __restrict__ tail_b,
            ushort* __restrict__ hsp, ushort* __restrict__ tsp) {
    const int sel = blockIdx.z;
    const ushort* WTp = sel ? WTt : WTh;
    const float* bias = sel ? tail_b : head_b;
    ushort* outp = sel ? tsp : hsp;

    const int n0 = blockIdx.x * 64, e0 = blockIdx.y * 64;
    const int tid = threadIdx.x, lane = tid & 63, wv = tid >> 6;
    const int col = lane & 15, g = lane >> 4;

    __shared__ int sbase[64];
    __shared__ ushort sA[64 * 72];
    __shared__ ushort sB[64 * 72];

    if (tid < 64) {
        int n = n0 + tid, bb = n / cR;
        sbase[tid] = (bb * cE + hts[n * 2 + sel]) * cH;
    }
    __syncthreads();

    float4v acc[4];
#pragma unroll
    for (int ct = 0; ct < 4; ct++) acc[ct] = (float4v){0.f, 0.f, 0.f, 0.f};

    for (int kt = 0; kt < 2 * cH; kt += 64) {
        const bool first = kt < cH;
#pragma unroll
        for (int p = 0; p < 2; p++) {
            int t = tid + p * 256;
            int row = t >> 3, seg = t & 7;
            const ushort* src = first
                ? &ent_bf[(size_t)sbase[row] + kt + seg * 8]
                : &relbf[(size_t)(n0 + row) * cH + (kt - cH) + seg * 8];
            *(short8*)&sA[row * 72 + seg * 8] = *(const short8*)src;
        }
#pragma unroll
        for (int p = 0; p < 2; p++) {
            int t = tid + p * 256;
            int c = t >> 3, seg = t & 7;
            *(short8*)&sB[c * 72 + seg * 8] =
                *(const short8*)&WTp[(size_t)(e0 + c) * (2 * cH) + kt + seg * 8];
        }
        __syncthreads();
        const int wrow = wv * 16;
#pragma unroll
        for (int k0 = 0; k0 < 64; k0 += 32) {
            short8 a0 = *(const short8*)&sA[(wrow + col) * 72 + k0 + g * 8];
#pragma unroll
            for (int ct = 0; ct < 4; ct++) {
                short8 bf = *(const short8*)&sB[(ct * 16 + col) * 72 + k0 + g * 8];
                acc[ct] = __builtin_amdgcn_mfma_f32_16x16x32_bf16(a0, bf, acc[ct], 0, 0, 0);
            }
        }
        __syncthreads();
    }
#pragma unroll
    for (int ct = 0; ct < 4; ct++) {
        int e = e0 + ct * 16 + col;
        float bv = bias[e];
        int rowb = n0 + wv * 16 + g * 4;
#pragma unroll
        for (int reg = 0; reg < 4; reg++)
            outp[(size_t)(rowb + reg) * cEMB + e] = f2bf(tanhf(acc[ct][reg] + bv));
    }
}

// ---------------------------------------------------------------------------
// Kernel 6a: out init with bias
__global__ void out_init_k(const float* __restrict__ bil_b, float* __restrict__ out) {
    int idx = blockIdx.x * 256 + threadIdx.x;
    if (idx < cN * cC) out[idx] = bil_b[idx % cC];
}

// ---------------------------------------------------------------------------
// Kernel 6b: bilinear v7 = v3 structure (97 µs verified) with the register
// cap REMOVED (__launch_bounds__(256), no min-waves). Theory: (256,2)'s
// 128-VGPR cap forced the allocator to sink the w0/w1 prefetch loads to
// their uses, collapsing the double-buffer. Actual residency is grid-limited
// (~5.4 waves/CU), not VGPR-limited, so extra VGPRs are free.
__global__ __launch_bounds__(256) void
bil_mfma7_k(const ushort* __restrict__ hsp, const ushort* __restrict__ tsp,
            const ushort* __restrict__ Wf, float* __restrict__ out) {
    const int islice = blockIdx.x;       // 0..23
    const int n0 = blockIdx.y * 128;
    const int kb = islice >> 1;          // ts column block
    const int tid = threadIdx.x;
    const int lane = tid & 63, wv = tid >> 6;
    const int col = lane & 15, g = lane >> 4;
    const int rh = wv >> 1, cth = wv & 1;

    __shared__ float sHs[32 * 132];      // [i][row]

    // stage hs tile -> f32 LDS, transposed
    for (int idx = tid; idx < 512; idx += 256) {
        int row = idx & 127, seg = idx >> 7;
        short8 v = *(const short8*)&hsp[(size_t)(n0 + row) * cEMB + islice * 32 + seg * 8];
#pragma unroll
        for (int jj = 0; jj < 8; jj++)
            sHs[(seg * 8 + jj) * 132 + row] = bf2f((ushort)v[jj]);
    }

    // ts A-fragments (held in registers for all 32 iterations)
    short8 tsA[4][2];
#pragma unroll
    for (int mt = 0; mt < 4; mt++)
#pragma unroll
        for (int kh = 0; kh < 2; kh++)
            tsA[mt][kh] = *(const short8*)
                &tsp[(size_t)(n0 + rh * 64 + mt * 16 + col) * cEMB + kb * 64 + kh * 32 + g * 8];

    float4v acc[4][4];
#pragma unroll
    for (int mt = 0; mt < 4; mt++)
#pragma unroll
        for (int ct = 0; ct < 4; ct++) acc[mt][ct] = (float4v){0.f, 0.f, 0.f, 0.f};

    const ushort* WfS = Wf + (size_t)islice * 32 * 8192;

#define WFRAG(i, ctl, kh) \
    (*(const short8*)&WfS[(((size_t)(i) * 16 + (kh) * 8 + cth * 4 + (ctl)) * 64 + lane) * 8])

    short8 w0[8], w1[8];
#pragma unroll
    for (int ctl = 0; ctl < 4; ctl++) {
        w0[ctl * 2 + 0] = WFRAG(0, ctl, 0);
        w0[ctl * 2 + 1] = WFRAG(0, ctl, 1);
    }
    __syncthreads();  // hs staged (the only barrier)

    for (int i = 0; i < 32; i += 2) {
        // prefetch i+1 while computing i
#pragma unroll
        for (int ctl = 0; ctl < 4; ctl++) {
            w1[ctl * 2 + 0] = WFRAG(i + 1, ctl, 0);
            w1[ctl * 2 + 1] = WFRAG(i + 1, ctl, 1);
        }
        {
            float4v hsv[4];
#pragma unroll
            for (int mt = 0; mt < 4; mt++)
                hsv[mt] = *(const float4v*)&sHs[i * 132 + rh * 64 + mt * 16 + g * 4];
#pragma unroll
            for (int ctl = 0; ctl < 4; ctl++) {
#pragma unroll
                for (int mt = 0; mt < 4; mt++) {
                    float4v P = (float4v){0.f, 0.f, 0.f, 0.f};
                    P = __builtin_amdgcn_mfma_f32_16x16x32_bf16(tsA[mt][0], w0[ctl * 2 + 0], P, 0, 0, 0);
                    P = __builtin_amdgcn_mfma_f32_16x16x32_bf16(tsA[mt][1], w0[ctl * 2 + 1], P, 0, 0, 0);
                    acc[mt][ctl] += hsv[mt] * P;
                }
            }
        }
        // prefetch i+2 while computing i+1
        if (i + 2 < 32) {
#pragma unroll
            for (int ctl = 0; ctl < 4; ctl++) {
                w0[ctl * 2 + 0] = WFRAG(i + 2, ctl, 0);
                w0[ctl * 2 + 1] = WFRAG(i + 2, ctl, 1);
            }
        }
        {
            float4v hsv[4];
#pragma unroll
            for (int mt = 0; mt < 4; mt++)
                hsv[mt] = *(const float4v*)&sHs[(i + 1) * 132 + rh * 64 + mt * 16 + g * 4];
#pragma unroll
            for (int ctl = 0; ctl < 4; ctl++) {
#pragma unroll
                for (int mt = 0; mt < 4; mt++) {
                    float4v P = (float4v){0.f, 0.f, 0.f, 0.f};
                    P = __builtin_amdgcn_mfma_f32_16x16x32_bf16(tsA[mt][0], w1[ctl * 2 + 0], P, 0, 0, 0);
                    P = __builtin_amdgcn_mfma_f32_16x16x32_bf16(tsA[mt][1], w1[ctl * 2 + 1], P, 0, 0, 0);
                    acc[mt][ctl] += hsv[mt] * P;
                }
            }
        }
    }
#undef WFRAG

    // epilogue: atomic combine over 24 slices
#pragma unroll
    for (int mt = 0; mt < 4; mt++) {
#pragma unroll
        for (int ctl = 0; ctl < 4; ctl++) {
            int c = (cth * 4 + ctl) * 16 + col;
            if (c < cC) {
                int rowb = n0 + rh * 64 + mt * 16 + g * 4;
#pragma unroll
                for (int reg = 0; reg < 4; reg++)
                    atomicAdd(&out[(size_t)(rowb + reg) * cC + c], acc[mt][ctl][reg]);
            }
        }
    }
}

// ---------------------------------------------------------------------------
extern "C" void kernel_launch(void* const* d_in, const int* in_sizes, int n_in,
                              void* d_out, int out_size, void* d_ws, size_t ws_size,
                              hipStream_t stream) {
    const float* seq_lhs  = (const float*)d_in[0];
    const float* ent_lhs  = (const float*)d_in[1];
    const float* attn     = (const float*)d_in[2];
    const int*   ids      = (const int*)d_in[3];
    const int*   hts      = (const int*)d_in[4];
    const float* head_W   = (const float*)d_in[5];
    const float* head_b   = (const float*)d_in[6];
    const float* tail_W   = (const float*)d_in[7];
    const float* tail_b   = (const float*)d_in[8];
    const float* bil_W    = (const float*)d_in[9];
    const float* bil_b    = (const float*)d_in[10];
    float* out = (float*)d_out;

    // workspace layout (byte offsets, 256B-aligned)
    char* ws = (char*)d_ws;
    int*    counts   = (int*)(ws + 0);             // 512 B
    ushort* ent_bf   = (ushort*)(ws + 512);        // 262144 B
    ushort* ent_attn = (ushort*)(ws + 262656);     // bf16, 4194304 B
    ushort* wbuf     = (ushort*)(ws + 4456960);    // 8126464 B
    ushort* relbf    = (ushort*)(ws + 12583424);   // 8126464 B
    ushort* hsp      = (ushort*)(ws + 20709888);   // 6094848 B
    ushort* tsp      = (ushort*)(ws + 26804736);   // 6094848 B
    ushort* Wf       = (ushort*)(ws + 32899584);   // 12582912 B
    ushort* WTh      = (ushort*)(ws + 45482496);   // 3145728 B
    ushort* WTt      = (ushort*)(ws + 48628224);   // 3145728 B
    ushort* seqT     = (ushort*)(ws + 51773952);   // 8388608 B  (end 60162560)

    hipLaunchKernelGGL(wf_build_k, dim3(768), dim3(256), 0, stream, bil_W, Wf);
    hipLaunchKernelGGL(tr_ht_k, dim3(64, 24, 2), dim3(256), 0, stream,
                       head_W, tail_W, WTh, WTt);
    hipLaunchKernelGGL(tr_bf16_k, dim3(32, 32, cB), dim3(256), 0, stream,
                       seq_lhs, seqT, cL, cH, cH);

    hipLaunchKernelGGL(ent_pool_k, dim3(cE, cB, 4), dim3(256), 0, stream,
                       ent_lhs, ids, ent_bf, counts);
    hipLaunchKernelGGL(ent_attn_k, dim3(cB * cA, cL / 256), dim3(256), 0, stream,
                       attn, ids, counts, ent_attn);
    hipLaunchKernelGGL(w_k, dim3(cN), dim3(256), 0, stream,
                       ent_attn, hts, wbuf);
    hipLaunchKernelGGL(rel_mfma_k, dim3(8, 16, cB), dim3(256), 0, stream,
                       wbuf, seqT, relbf);
    hipLaunchKernelGGL(proj_mfma_k, dim3(cN / 64, cEMB / 64, 2), dim3(256), 0, stream,
                       ent_bf, relbf, hts, WTh, WTt, head_b, tail_b, hsp, tsp);
    hipLaunchKernelGGL(out_init_k, dim3((cN * cC + 255) / 256), dim3(256), 0, stream,
                       bil_b, out);
    hipLaunchKernelGGL(bil_mfma7_k, dim3(24, cN / 128), dim3(256), 0, stream,
                       hsp, tsp, Wf, out);
}